// Round 17
// baseline (290.242 us; speedup 1.0000x reference)
//
#include <hip/hip_runtime.h>
#include <stdint.h>

#define HH 16
#define DH 64
#define DD 1024
#define PP 1024
#define NNLEN 8192
#define BBATCH 2
#define MM (BBATCH*NNLEN)   // 16384 rows
#define CCHUNK 128          // chunks per (b,h)
#define LCH 64              // chunk length
#define NGRP 16             // scan groups per (b,h)
#define GCH 8               // chunks per group
#define EPSV 1e-6f

typedef unsigned short u16;
typedef __attribute__((ext_vector_type(4))) unsigned short u16x4;
typedef __attribute__((ext_vector_type(8))) unsigned short u16x8;
typedef __attribute__((ext_vector_type(8))) __bf16 bf16x8;
typedef __attribute__((ext_vector_type(4))) float f32x4;

__device__ __forceinline__ u16 f2bf(float f) {
  unsigned x = __float_as_uint(f);
  return (u16)((x + 0x7fffu + ((x >> 16) & 1u)) >> 16);
}
__device__ __forceinline__ float bf2f(u16 u) {
  return __uint_as_float(((unsigned)u) << 16);
}

// async global->LDS, 16B per lane. LDS dest must be wave-uniform base.
__device__ __forceinline__ void gl2lds16(const void* g, void* l) {
  __builtin_amdgcn_global_load_lds(
      reinterpret_cast<__attribute__((address_space(1))) void*>(
          reinterpret_cast<uintptr_t>(g)),
      reinterpret_cast<__attribute__((address_space(3))) void*>(
          reinterpret_cast<uintptr_t>(l)),
      16, 0, 0);
}

// swizzled LDS read of a bf16x8 fragment from a [*][64] u16 tile.
__device__ __forceinline__ bf16x8 ldsw(const u16* base, int row, int col) {
  union { u16x8 u; bf16x8 b; } cv;
  cv.u = *(const u16x8*)&base[row * 64 + (col ^ ((row & 7) << 3))];
  return cv.b;
}

// ---------------------------------------------------------------------------
// prep_all v3 (single launch):
//   blocks [0,256):      fused x f32->bf16 convert (64 rows each) + a_proj
//                        (abuf = sigmoid(x @ Wa + ba + 2), Wa read f32 direct)
//   blocks [256,4352):   four 1024x1024 transposes f32->bf16 (Wq,Wk,Wv,Wo)
// ---------------------------------------------------------------------------
__global__ __launch_bounds__(256)
void prep_all(const float* __restrict__ x, u16* __restrict__ xb,
              const float* __restrict__ Wq, u16* __restrict__ WqT,
              const float* __restrict__ Wk, u16* __restrict__ WkT,
              const float* __restrict__ Wv, u16* __restrict__ WvT,
              const float* __restrict__ Wo, u16* __restrict__ WoT,
              const float* __restrict__ Wa, const float* __restrict__ ba,
              float* __restrict__ abuf) {
  const int bid = blockIdx.x;
  const int tid = threadIdx.x;
  if (bid < 256) {
    // fused x-convert + a_proj: 64 rows per block
    __shared__ __align__(16) u16 As[64 * 40];   // stride 40 u16 (80B): 2-way max
    const int brow = bid * 64;
    const int row = tid >> 2, col8 = (tid & 3) * 8;
    const int l = tid & 63, wid = tid >> 6;
    const int la = l & 15, kb8 = (l >> 4) * 8;
    f32x4 acc = (f32x4){0.f, 0.f, 0.f, 0.f};
    for (int kt = 0; kt < 32; ++kt) {
      const int k0 = kt * 32;
      const float* xr = x + (size_t)(brow + row) * DD + k0 + col8;
      f32x4 a = *(const f32x4*)xr;
      f32x4 b2 = *(const f32x4*)(xr + 4);
      u16x8 o;
      o[0] = f2bf(a[0]);  o[1] = f2bf(a[1]);  o[2] = f2bf(a[2]);  o[3] = f2bf(a[3]);
      o[4] = f2bf(b2[0]); o[5] = f2bf(b2[1]); o[6] = f2bf(b2[2]); o[7] = f2bf(b2[3]);
      *(u16x8*)(xb + (size_t)(brow + row) * DD + k0 + col8) = o;
      if (kt) __syncthreads();            // prior iter's As reads done
      *(u16x8*)&As[row * 40 + col8] = o;
      __syncthreads();                    // As ready
      union { u16x8 u; bf16x8 b; } cvb, cva;
#pragma unroll
      for (int j = 0; j < 8; ++j)
        cvb.u[j] = f2bf(Wa[(size_t)(k0 + kb8 + j) * HH + la]);
      cva.u = *(const u16x8*)&As[(wid * 16 + la) * 40 + kb8];
      acc = __builtin_amdgcn_mfma_f32_16x16x32_bf16(cva.b, cvb.b, acc, 0, 0, 0);
    }
    const float bav = ba[la];
#pragma unroll
    for (int rr = 0; rr < 4; ++rr) {
      int row2 = brow + wid * 16 + ((l >> 4) << 2) + rr;
      float t = acc[rr] + bav + 2.0f;
      abuf[(size_t)row2 * HH + la] = 1.f / (1.f + __expf(-t));
    }
    return;
  }
  {
    __shared__ float tile[32][33];
    const int bid2 = bid - 256;
    const int t = bid2 >> 10;
    const int sub = bid2 & 1023;
    const float* in = (t == 0) ? Wq : (t == 1) ? Wk : (t == 2) ? Wv : Wo;
    u16* out = (t == 0) ? WqT : (t == 1) ? WkT : (t == 2) ? WvT : WoT;
    const int bx = (sub & 31) * 32, by = (sub >> 5) * 32;
    const int tx = tid & 31, ty = tid >> 5;
    for (int i2 = ty; i2 < 32; i2 += 8)
      tile[i2][tx] = in[(size_t)(by + i2) * 1024 + bx + tx];
    __syncthreads();
    for (int i2 = ty; i2 < 32; i2 += 8)
      out[(size_t)(bx + i2) * 1024 + by + tx] = f2bf(tile[tx][i2]);
  }
}

// ---------------------------------------------------------------------------
// bf16 MFMA GEMM, 16-wave / 4-waves-per-SIMD (r14-verified: 1035 TF):
// 256x256 tile, BK=64, minimal-barrier stage-first, ONE vmcnt(0)+barrier
// per K-tile. Fused QKV (N=3072) routed bf16 epilogue w/ elu+1 on q/k.
// ---------------------------------------------------------------------------
template<int NCT>
__global__ __launch_bounds__(1024, 4)
void gemm16(const u16* __restrict__ A, const u16* __restrict__ Bt,
            void* __restrict__ Cout) {
  __shared__ __align__(16) u16 As[2][256 * 64];
  __shared__ __align__(16) u16 Bs[2][256 * 64];
  const int tid = threadIdx.x;
  const int nwg = gridDim.x;
  const int f = blockIdx.x;
  const int swz = (f & 7) * (nwg >> 3) + (f >> 3);
  const int brow = (swz / NCT) * 256;
  const int bcol = (swz % NCT) * 256;
  const int l = tid & 63;
  const int wid = tid >> 6;       // 0..15
  const int wr = wid >> 2;        // 0..3  (M quarter)
  const int wc = wid & 3;         // 0..3  (N quarter)
  const int la = l & 15, kb8 = (l >> 4) * 8;
  const int K = 1024;
  const int srow = l >> 3;
  const int scol = ((l & 7) * 8) ^ (srow << 3);
  const int ldso = (wid * 2) * 512;

  f32x4 acc[4][4];
#pragma unroll
  for (int i = 0; i < 4; ++i)
#pragma unroll
    for (int j = 0; j < 4; ++j) acc[i][j] = (f32x4){0.f, 0.f, 0.f, 0.f};

#pragma unroll
  for (int j = 0; j < 2; ++j) {
    const int r0 = (wid * 2 + j) * 8 + srow;
    gl2lds16(A  + (size_t)(brow + r0) * K + scol, &As[0][ldso + j * 512]);
    gl2lds16(Bt + (size_t)(bcol + r0) * K + scol, &Bs[0][ldso + j * 512]);
  }
  asm volatile("s_waitcnt vmcnt(0)" ::: "memory");
  __builtin_amdgcn_s_barrier();

  const int NKT = K / 64;
  for (int kt = 0; kt < NKT; ++kt) {
    const u16* lA = As[kt & 1];
    const u16* lB = Bs[kt & 1];
    u16* nA = As[(kt + 1) & 1];
    u16* nB = Bs[(kt + 1) & 1];
    const int knext = (kt + 1) * 64;
    const bool more = (kt + 1 < NKT);

    if (more) {
#pragma unroll
      for (int j = 0; j < 2; ++j) {
        const int r0 = (wid * 2 + j) * 8 + srow;
        gl2lds16(A  + (size_t)(brow + r0) * K + knext + scol,
                 nA + ldso + j * 512);
        gl2lds16(Bt + (size_t)(bcol + r0) * K + knext + scol,
                 nB + ldso + j * 512);
      }
    }

    bf16x8 bfr[4][2];
#pragma unroll
    for (int n2 = 0; n2 < 4; ++n2)
#pragma unroll
      for (int kk = 0; kk < 2; ++kk)
        bfr[n2][kk] = ldsw(lB, wc * 64 + n2 * 16 + la, kk * 32 + kb8);

#pragma unroll
    for (int m2 = 0; m2 < 4; ++m2) {
      bf16x8 af0 = ldsw(lA, wr * 64 + m2 * 16 + la, kb8);
      bf16x8 af1 = ldsw(lA, wr * 64 + m2 * 16 + la, 32 + kb8);
      __builtin_amdgcn_s_setprio(1);
#pragma unroll
      for (int n2 = 0; n2 < 4; ++n2) {
        acc[m2][n2] = __builtin_amdgcn_mfma_f32_16x16x32_bf16(
            af0, bfr[n2][0], acc[m2][n2], 0, 0, 0);
        acc[m2][n2] = __builtin_amdgcn_mfma_f32_16x16x32_bf16(
            af1, bfr[n2][1], acc[m2][n2], 0, 0, 0);
      }
      __builtin_amdgcn_s_setprio(0);
    }

    if (more) {
      asm volatile("s_waitcnt vmcnt(0)" ::: "memory");
      __builtin_amdgcn_s_barrier();
    }
  }

  const int wrow = wr * 64, wcol = wc * 64;
  u16* base = (u16*)Cout + (size_t)(bcol >> 10) * ((size_t)MM * 1024);
  const bool act = (bcol < 2048);
#pragma unroll
  for (int mi = 0; mi < 4; ++mi)
#pragma unroll
    for (int ni = 0; ni < 4; ++ni)
#pragma unroll
      for (int rr = 0; rr < 4; ++rr) {
        int row = brow + wrow + mi * 16 + ((l >> 4) << 2) + rr;
        int c2 = (bcol & 1023) + wcol + ni * 16 + la;
        float v = acc[mi][ni][rr];
        if (act) v = v > 0.f ? v + 1.f : __expf(v);
        base[(size_t)row * 1024 + c2] = f2bf(v);
      }
}

// ---------------------------------------------------------------------------
// bf16 MFMA GEMM, 8-wave / 512-thread (r9-verified for Wo, f32 out).
// ---------------------------------------------------------------------------
template<int NCT>
__global__ __launch_bounds__(512)
void gemm_db(const u16* __restrict__ A, const u16* __restrict__ Bt,
             float* __restrict__ Cout) {
  __shared__ __align__(16) u16 As[2][256 * 64];
  __shared__ __align__(16) u16 Bs[2][256 * 64];
  const int tid = threadIdx.x;
  const int nwg = gridDim.x;
  const int f = blockIdx.x;
  const int swz = (f & 7) * (nwg >> 3) + (f >> 3);
  const int brow = (swz / NCT) * 256;
  const int bcol = (swz % NCT) * 256;
  const int l = tid & 63;
  const int wid = tid >> 6;
  const int wr = wid >> 2;
  const int wc = wid & 3;
  const int la = l & 15, kb8 = (l >> 4) * 8;
  const int K = 1024;
  const int srow = l >> 3;
  const int scol = ((l & 7) * 8) ^ (srow << 3);
  const int ldso = (wid * 2) * 512;

  f32x4 acc[8][4];
#pragma unroll
  for (int i = 0; i < 8; ++i)
#pragma unroll
    for (int j = 0; j < 4; ++j) acc[i][j] = (f32x4){0.f, 0.f, 0.f, 0.f};

#pragma unroll
  for (int h = 0; h < 2; ++h)
#pragma unroll
    for (int j = 0; j < 2; ++j) {
      const int r0 = h * 128 + (wid * 2 + j) * 8 + srow;
      gl2lds16(A  + (size_t)(brow + r0) * K + scol, &As[0][h * 8192 + ldso + j * 512]);
      gl2lds16(Bt + (size_t)(bcol + r0) * K + scol, &Bs[0][h * 8192 + ldso + j * 512]);
    }
  asm volatile("s_waitcnt vmcnt(0)" ::: "memory");
  __builtin_amdgcn_s_barrier();

  const int NKT = K / 64;
  for (int kt = 0; kt < NKT; ++kt) {
    const u16* lA = As[kt & 1];
    const u16* lB = Bs[kt & 1];
    u16* nA = As[(kt + 1) & 1];
    u16* nB = Bs[(kt + 1) & 1];
    const int knext = (kt + 1) * 64;
    const bool more = (kt + 1 < NKT);

    if (more) {
#pragma unroll
      for (int h = 0; h < 2; ++h)
#pragma unroll
        for (int j = 0; j < 2; ++j) {
          const int r0 = h * 128 + (wid * 2 + j) * 8 + srow;
          gl2lds16(A  + (size_t)(brow + r0) * K + knext + scol,
                   nA + h * 8192 + ldso + j * 512);
          gl2lds16(Bt + (size_t)(bcol + r0) * K + knext + scol,
                   nB + h * 8192 + ldso + j * 512);
        }
    }

    bf16x8 af[4][2], bfr[4][2];
#pragma unroll
    for (int m2 = 0; m2 < 4; ++m2)
#pragma unroll
      for (int kk = 0; kk < 2; ++kk)
        af[m2][kk] = ldsw(lA, wr * 128 + m2 * 16 + la, kk * 32 + kb8);
#pragma unroll
    for (int n2 = 0; n2 < 4; ++n2)
#pragma unroll
      for (int kk = 0; kk < 2; ++kk)
        bfr[n2][kk] = ldsw(lB, wc * 64 + n2 * 16 + la, kk * 32 + kb8);

    __builtin_amdgcn_s_setprio(1);
#pragma unroll
    for (int m2 = 0; m2 < 4; ++m2)
#pragma unroll
      for (int n2 = 0; n2 < 4; ++n2)
#pragma unroll
        for (int kk = 0; kk < 2; ++kk)
          acc[m2][n2] = __builtin_amdgcn_mfma_f32_16x16x32_bf16(
              af[m2][kk], bfr[n2][kk], acc[m2][n2], 0, 0, 0);
    __builtin_amdgcn_s_setprio(0);

#pragma unroll
    for (int m2 = 0; m2 < 4; ++m2)
#pragma unroll
      for (int kk = 0; kk < 2; ++kk)
        af[m2][kk] = ldsw(lA, wr * 128 + 64 + m2 * 16 + la, kk * 32 + kb8);

    __builtin_amdgcn_s_setprio(1);
#pragma unroll
    for (int m2 = 0; m2 < 4; ++m2)
#pragma unroll
      for (int n2 = 0; n2 < 4; ++n2)
#pragma unroll
        for (int kk = 0; kk < 2; ++kk)
          acc[4 + m2][n2] = __builtin_amdgcn_mfma_f32_16x16x32_bf16(
              af[m2][kk], bfr[n2][kk], acc[4 + m2][n2], 0, 0, 0);
    __builtin_amdgcn_s_setprio(0);

    if (more) {
      asm volatile("s_waitcnt vmcnt(0)" ::: "memory");
      __builtin_amdgcn_s_barrier();
    }
  }

  const int wrow = wr * 128, wcol = wc * 64;
#pragma unroll
  for (int mi = 0; mi < 8; ++mi)
#pragma unroll
    for (int ni = 0; ni < 4; ++ni)
#pragma unroll
      for (int rr = 0; rr < 4; ++rr) {
        int row = brow + wrow + mi * 16 + ((l >> 4) << 2) + rr;
        int col = bcol + wcol + ni * 16 + la;
        Cout[(size_t)row * 1024 + col] = acc[mi][ni][rr];
      }
}

// ---------------------------------------------------------------------------
// FUSED Kernel A + scan level 1, cA-hoisted + k/v software pipeline.
// ---------------------------------------------------------------------------
__global__ __launch_bounds__(256)
void chunk_local_scan(const u16* __restrict__ kb, const u16* __restrict__ vb,
                      const float* __restrict__ abuf,
                      u16* __restrict__ Sbuf, float* __restrict__ zbuf,
                      float* __restrict__ cAbuf,
                      float* __restrict__ GAgg, float* __restrict__ zGAgg,
                      float* __restrict__ dpbuf) {
  const int g = blockIdx.x & (NGRP - 1);
  const int bh = blockIdx.x >> 4;
  const int h = bh & (HH - 1);
  const int b = bh >> 4;
  __shared__ __align__(16) u16 KT[64 * 64];
  __shared__ __align__(16) u16 VTl[64 * 64];
  __shared__ float wshA[GCH][64];
  __shared__ float dchA[GCH];
  const int tid = threadIdx.x;
  const int r = tid >> 2, e = (tid & 3) * 16;
  const int l = tid & 63, w = tid >> 6;
  const int kb8 = (l >> 4) << 3, la = l & 15;
  const int dw = 16 * w + ((l >> 4) << 2);
  const int dkz = tid >> 2, tqz = (tid & 3) * 16, swkz = (dkz & 7) << 3;
  const int c0 = g * GCH;
  const int rowbase0 = b * NNLEN + c0 * LCH;

#pragma unroll
  for (int ii = 0; ii < 2; ++ii) {
    const int i = w * 2 + ii;
    const int blkc = bh * CCHUNK + c0 + i;
    float v = __logf(abuf[(size_t)(rowbase0 + i * LCH + l) * HH + h]);
#pragma unroll
    for (int d = 1; d < 64; d <<= 1) {
      float u = __shfl_up(v, d);
      if (l >= d) v += u;
    }
    cAbuf[(size_t)blkc * 64 + l] = v;
    float tot = __shfl(v, 63);
    wshA[i][l] = __expf(tot - v);
    if (l == 0) dchA[i] = __expf(tot);
  }
  __syncthreads();
  if (tid == 0) {
    float rp = 1.f;
#pragma unroll
    for (int i = 0; i < GCH; ++i) {
      dpbuf[bh * CCHUNK + c0 + i] = rp;
      rp *= dchA[i];
    }
  }

  f32x4 run[4];
#pragma unroll
  for (int ni = 0; ni < 4; ++ni) run[ni] = (f32x4){0.f, 0.f, 0.f, 0.f};
  float zrun = 0.f;

  const u16* kp = kb + (size_t)(rowbase0 + r) * PP + h * DH + e;
  const u16* vp = vb + (size_t)(rowbase0 + r) * PP + h * DH + e;
  u16x8 k0 = *(const u16x8*)kp, k1 = *(const u16x8*)(kp + 8);
  u16x8 v0 = *(const u16x8*)vp, v1 = *(const u16x8*)(vp + 8);

  for (int i = 0; i < GCH; ++i) {
    const int blkc = bh * CCHUNK + c0 + i;
    if (i) __syncthreads();

    {
      const float wt = wshA[i][r];
#pragma unroll
      for (int j = 0; j < 8; ++j) {
        int d0 = e + j, d1 = e + 8 + j;
        KT[d0 * 64 + (r ^ ((d0 & 7) << 3))] = f2bf(bf2f(k0[j]) * wt);
        KT[d1 * 64 + (r ^ ((d1 & 7) << 3))] = f2bf(bf2f(k1[j]) * wt);
        VTl[d0 * 64 + (r ^ ((d0 & 7) << 3))] = v0[j];
        VTl[d1 * 64 + (r ^ ((d1 & 7) << 3))] = v1[j];
      }
    }
    __syncthreads();

    if (i + 1 < GCH) {
      const int rb = rowbase0 + (i + 1) * LCH;
      kp = kb + (size_t)(rb + r) * PP + h * DH + e;
      vp = vb + (size_t)(rb + r) * PP + h * DH + e;
      k0 = *(const u16x8*)kp; k1 = *(const u16x8*)(kp + 8);
      v0 = *(const u16x8*)vp; v1 = *(const u16x8*)(vp + 8);
    }

    const float dch = dchA[i];
    f32x4 s[4];
#pragma unroll
    for (int ni = 0; ni < 4; ++ni) s[ni] = (f32x4){0.f, 0.f, 0.f, 0.f};
#pragma unroll
    for (int kk = 0; kk < 2; ++kk) {
      bf16x8 av = ldsw(VTl, 16 * w + la, kk * 32 + kb8);
#pragma unroll
      for (int ni = 0; ni < 4; ++ni)
        s[ni] = __builtin_amdgcn_mfma_f32_16x16x32_bf16(
            av, ldsw(KT, 16 * ni + la, kk * 32 + kb8), s[ni], 0, 0, 0);
    }

    u16* Sc = Sbuf + (size_t)blkc * 4096;
#pragma unroll
    for (int ni = 0; ni < 4; ++ni)
#pragma unroll
      for (int rr = 0; rr < 4; ++rr)
        Sc[(dw + rr) * 64 + 16 * ni + la] = f2bf(run[ni][rr]);
#pragma unroll
    for (int ni = 0; ni < 4; ++ni)
#pragma unroll
      for (int rr = 0; rr < 4; ++rr)
        run[ni][rr] = dch * run[ni][rr] + s[ni][rr];

    {
      float zp = 0.f;
#pragma unroll
      for (int i2 = 0; i2 < 16; ++i2)
        zp += bf2f(KT[dkz * 64 + ((tqz + i2) ^ swkz)]);
      zp += __shfl_xor(zp, 1);
      zp += __shfl_xor(zp, 2);
      if ((tid & 3) == 0) zbuf[(size_t)blkc * 64 + dkz] = zrun;
      zrun = dch * zrun + zp;
    }
  }

  float* Ga = GAgg + ((size_t)bh * NGRP + g) * 4096;
#pragma unroll
  for (int ni = 0; ni < 4; ++ni)
#pragma unroll
    for (int rr = 0; rr < 4; ++rr)
      Ga[(dw + rr) * 64 + 16 * ni + la] = run[ni][rr];
  if ((tid & 3) == 0)
    zGAgg[((size_t)bh * NGRP + g) * 64 + dkz] = zrun;
}

// ---------------------------------------------------------------------------
// Scan level 2: across the 16 group aggregates. GAgg(f32) -> GBeg (bf16).
// ---------------------------------------------------------------------------
__global__ __launch_bounds__(1024)
void scan_top(const float* __restrict__ GAgg, u16* __restrict__ GBeg,
              float* __restrict__ zGAgg, const float* __restrict__ cAbuf) {
  const int bh = blockIdx.x;
  const size_t cb = (size_t)bh * CCHUNK;
  __shared__ float Dsh[NGRP];
  if (threadIdx.x < NGRP) {
    float s = 0.f;
#pragma unroll
    for (int i = 0; i < GCH; ++i)
      s += cAbuf[(cb + threadIdx.x * GCH + i) * 64 + 63];
    Dsh[threadIdx.x] = __expf(s);
  }
  __syncthreads();
  const int elem = threadIdx.x * 4;
  const float* base = GAgg + (size_t)bh * NGRP * 4096;
  u16* gb = GBeg + (size_t)bh * NGRP * 4096;
  f32x4 run = (f32x4){0.f, 0.f, 0.f, 0.f};
  f32x4 cur = *(const f32x4*)&base[elem];
#pragma unroll
  for (int gg = 0; gg < NGRP; ++gg) {
    f32x4 nxt;
    if (gg + 1 < NGRP) nxt = *(const f32x4*)&base[(gg + 1) * 4096 + elem];
    u16x4 o;
#pragma unroll
    for (int jj = 0; jj < 4; ++jj) o[jj] = f2bf(run[jj]);
    *(u16x4*)&gb[gg * 4096 + elem] = o;
    const float D = Dsh[gg];
#pragma unroll
    for (int jj = 0; jj < 4; ++jj) run[jj] = D * run[jj] + cur[jj];
    cur = nxt;
  }
  if (threadIdx.x < 64) {
    float* zb = zGAgg + (size_t)bh * NGRP * 64;
    float zr = 0.f;
#pragma unroll
    for (int gg = 0; gg < NGRP; ++gg) {
      float a = zb[gg * 64 + threadIdx.x];
      zb[gg * 64 + threadIdx.x] = zr;
      zr = Dsh[gg] * zr + a;
    }
  }
}

// ---------------------------------------------------------------------------
// Kernel C v2 (MFMA, tile-free operands): per-chunk output.
// Q/K/S0/GBeg loaded global->reg in FRAGMENT layout (scaled in regs);
// only V (transpose) and P (layout change) use LDS. All LDS dependencies
// after the single prologue barrier are wave-local. 17KB LDS.
// ---------------------------------------------------------------------------
__global__ __launch_bounds__(256)
void chunk_out(u16* __restrict__ qb, const u16* __restrict__ kb,
               const u16* __restrict__ vb, const u16* __restrict__ Sbuf,
               const float* __restrict__ zbuf, const float* __restrict__ cAbuf,
               const u16* __restrict__ GBeg, const float* __restrict__ zGAgg,
               const float* __restrict__ dpbuf) {
  const int blk = blockIdx.x;
  const int c = blk & (CCHUNK - 1);
  const int h = (blk >> 7) & (HH - 1);
  const int b = blk >> 11;
  const int bh = blk >> 7;
  const int g = c >> 3;
  const int rowbase = b * NNLEN + c * LCH;

  __shared__ __align__(16) u16 VT[64 * 64];   // V^T[dv][s] swizzled
  __shared__ __align__(16) u16 Pb[64 * 64];   // P[t][s] swizzled (wave-local)
  __shared__ float cAsh[64], zsh[64], qzs[64];

  const int tid = threadIdx.x;
  const int r = tid >> 2, e = (tid & 3) * 16;
  const float dp = dpbuf[blk];

  // prologue: V transpose into LDS + cA/z (scaled)
  const u16* vp = vb + (size_t)(rowbase + r) * PP + h * DH + e;
  u16x8 v0 = *(const u16x8*)vp, v1 = *(const u16x8*)(vp + 8);
  if (tid < 64) {
    float ca = cAbuf[(size_t)blk * 64 + tid];
    cAsh[tid] = ca;
    float c0 = cAbuf[(size_t)blk * 64 + 31];
    zsh[tid] = (zbuf[(size_t)blk * 64 + tid]
              + dp * zGAgg[((size_t)bh * NGRP + g) * 64 + tid]) * __expf(c0);
  }
#pragma unroll
  for (int j = 0; j < 8; ++j) {
    int d0 = e + j, d1 = e + 8 + j;
    VT[d0 * 64 + (r ^ ((d0 & 7) << 3))] = v0[j];
    VT[d1 * 64 + (r ^ ((d1 & 7) << 3))] = v1[j];
  }
  __syncthreads();   // the ONLY block-wide barrier

  const int l = tid & 63, w = tid >> 6;
  const int kb8 = (l >> 4) << 3, la = l & 15;
  const int tw = 16 * w + ((l >> 4) << 2);
  const float c0c = cAsh[31];

  // Q frags from global, scaled (wave-local rows 16w+la)
  bf16x8 aq[2];
  {
    const float qsc = __expf(cAsh[16 * w + la] - c0c);
    const u16* qp = qb + (size_t)(rowbase + 16 * w + la) * PP + h * DH;
#pragma unroll
    for (int kk = 0; kk < 2; ++kk) {
      u16x8 q8 = *(const u16x8*)(qp + kk * 32 + kb8);
      union { u16x8 u; bf16x8 b; } cv;
#pragma unroll
      for (int j = 0; j < 8; ++j) cv.u[j] = f2bf(bf2f(q8[j]) * qsc);
      aq[kk] = cv.b;
    }
  }

  // --- MFMA1: P = Qe @ Ke^T (K frags from global, scaled) ---
  f32x4 p[4];
#pragma unroll
  for (int ni = 0; ni < 4; ++ni) p[ni] = (f32x4){0.f, 0.f, 0.f, 0.f};
#pragma unroll
  for (int ni = 0; ni < 4; ++ni) {
    const float ksc = __expf(c0c - cAsh[16 * ni + la]);
    const u16* kp = kb + (size_t)(rowbase + 16 * ni + la) * PP + h * DH;
#pragma unroll
    for (int kk = 0; kk < 2; ++kk) {
      u16x8 k8 = *(const u16x8*)(kp + kk * 32 + kb8);
      union { u16x8 u; bf16x8 b; } cv;
#pragma unroll
      for (int j = 0; j < 8; ++j) cv.u[j] = f2bf(bf2f(k8[j]) * ksc);
      p[ni] = __builtin_amdgcn_mfma_f32_16x16x32_bf16(aq[kk], cv.b, p[ni], 0, 0, 0);
    }
  }

  // mask + rowsum (stays in registers: butterfly leaves totals in all lanes)
  float rsum[4] = {0.f, 0.f, 0.f, 0.f};
#pragma unroll
  for (int ni = 0; ni < 4; ++ni)
#pragma unroll
    for (int rr = 0; rr < 4; ++rr) {
      int s = 16 * ni + la, t = tw + rr;
      float v = (s <= t) ? p[ni][rr] : 0.f;
      p[ni][rr] = v;
      rsum[rr] += v;
    }
#pragma unroll
  for (int d = 1; d < 16; d <<= 1)
#pragma unroll
    for (int rr = 0; rr < 4; ++rr) rsum[rr] += __shfl_xor(rsum[rr], d);

  // qz[row 16w+la] = Qe . z0e (zsh read after barrier; qzs write wave-local)
  {
    float qzp = 0.f;
#pragma unroll
    for (int kk = 0; kk < 2; ++kk) {
      union { bf16x8 b; u16x8 u; } cv; cv.b = aq[kk];
#pragma unroll
      for (int j = 0; j < 8; ++j)
        qzp += bf2f(cv.u[j]) * zsh[kk * 32 + kb8 + j];
    }
    qzp += __shfl_xor(qzp, 16);
    qzp += __shfl_xor(qzp, 32);
    if (l < 16) qzs[16 * w + la] = qzp;
  }

  // write P into Pb (wave-local rows; same-wave RAW ordered by lgkmcnt)
#pragma unroll
  for (int ni = 0; ni < 4; ++ni)
#pragma unroll
    for (int rr = 0; rr < 4; ++rr) {
      int t = tw + rr, s = 16 * ni + la;
      Pb[t * 64 + (s ^ ((t & 7) << 3))] = f2bf(p[ni][rr]);
    }

  // --- MFMA2: O = P@V + Qe@S0e^T (S0 frags from global) ---
  f32x4 o[4];
#pragma unroll
  for (int ni = 0; ni < 4; ++ni) o[ni] = (f32x4){0.f, 0.f, 0.f, 0.f};
#pragma unroll
  for (int kk = 0; kk < 2; ++kk) {
    bf16x8 ap = ldsw(Pb, 16 * w + la, kk * 32 + kb8);
#pragma unroll
    for (int ni = 0; ni < 4; ++ni)
      o[ni] = __builtin_amdgcn_mfma_f32_16x16x32_bf16(
          ap, ldsw(VT, 16 * ni + la, kk * 32 + kb8), o[ni], 0, 0, 0);
  }
  {
    const float ssc = __expf(c0c);
#pragma unroll
    for (int ni = 0; ni < 4; ++ni) {
      const u16* sp = Sbuf + (size_t)blk * 4096 + (16 * ni + la) * 64;
      const u16* gp = GBeg + ((size_t)bh * NGRP + g) * 4096 + (16 * ni + la) * 64;
#pragma unroll
      for (int kk = 0; kk < 2; ++kk) {
        u16x8 s8 = *(const u16x8*)(sp + kk * 32 + kb8);
        u16x8 g8 = *(const u16x8*)(gp + kk * 32 + kb8);
        union { u16x8 u; bf16x8 b; } cv;
#pragma unroll
        for (int j = 0; j < 8; ++j)
          cv.u[j] = f2bf((bf2f(s8[j]) + dp * bf2f(g8[j])) * ssc);
        o[ni] = __builtin_amdgcn_mfma_f32_16x16x32_bf16(aq[kk], cv.b, o[ni], 0, 0, 0);
      }
    }
  }

  float dn[4];
#pragma unroll
  for (int rr = 0; rr < 4; ++rr) dn[rr] = qzs[tw + rr] + rsum[rr] + EPSV;
#pragma unroll
  for (int ni = 0; ni < 4; ++ni)
#pragma unroll
    for (int rr = 0; rr < 4; ++rr) {
      int t = tw + rr, dv = 16 * ni + la;
      qb[(size_t)(rowbase + t) * PP + h * DH + dv] = f2bf(o[ni][rr] / dn[rr]);
    }
}

// ---------------------------------------------------------------------------
extern "C" void kernel_launch(void* const* d_in, const int* in_sizes, int n_in,
                              void* d_out, int out_size, void* d_ws, size_t ws_size,
                              hipStream_t stream) {
  const float* x  = (const float*)d_in[0];
  const float* Wq = (const float*)d_in[1];
  const float* Wk = (const float*)d_in[2];
  const float* Wv = (const float*)d_in[3];
  const float* Wo = (const float*)d_in[4];
  const float* Wa = (const float*)d_in[5];
  const float* ba = (const float*)d_in[6];

  char* ws = (char*)d_ws;
  size_t off = 0;
  auto carve = [&](size_t bytes) {
    void* p = ws + off;
    off += (bytes + 255) & ~(size_t)255;
    return p;
  };
  u16* xb   = (u16*)carve((size_t)MM * DD * 2);
  u16* WqT  = (u16*)carve((size_t)PP * DD * 2);  // WqT/WkT/WvT contiguous
  u16* WkT  = (u16*)carve((size_t)PP * DD * 2);
  u16* WvT  = (u16*)carve((size_t)PP * DD * 2);
  u16* WoT  = (u16*)carve((size_t)DD * PP * 2);
  u16* qb   = (u16*)carve((size_t)MM * PP * 2);  // qb/kb/vb contiguous
  u16* kb   = (u16*)carve((size_t)MM * PP * 2);
  u16* vb   = (u16*)carve((size_t)MM * PP * 2);
  float* abuf  = (float*)carve((size_t)MM * HH * 4);
  u16*  Sbuf   = (u16*)carve((size_t)BBATCH * HH * CCHUNK * 4096 * 2);
  float* zbuf  = (float*)carve((size_t)BBATCH * HH * CCHUNK * 64 * 4);
  float* cAbuf = (float*)carve((size_t)BBATCH * HH * CCHUNK * 64 * 4);
  float* GAgg  = (float*)carve((size_t)BBATCH * HH * NGRP * 4096 * 4);
  u16*  GBeg   = (u16*)carve((size_t)BBATCH * HH * NGRP * 4096 * 2);
  float* zGAgg = (float*)carve((size_t)BBATCH * HH * NGRP * 64 * 4);
  float* dpbuf = (float*)carve((size_t)BBATCH * HH * CCHUNK * 4);

  // fused prep: x convert + a_proj (256 blocks) + 4 transposes (4096 blocks)
  prep_all<<<4352, 256, 0, stream>>>(x, xb, Wq, WqT, Wk, WkT, Wv, WvT,
                                     Wo, WoT, Wa, ba, abuf);

  // fused QKV: M=16384, N=3072, 16-wave blocks (r14-verified 1035 TF)
  gemm16<12><<<(MM / 256) * 12, 1024, 0, stream>>>(xb, WqT, qb);

  chunk_local_scan<<<BBATCH * HH * NGRP, 256, 0, stream>>>(
      kb, vb, abuf, Sbuf, zbuf, cAbuf, GAgg, zGAgg, dpbuf);
  scan_top<<<BBATCH * HH, 1024, 0, stream>>>(GAgg, GBeg, zGAgg, cAbuf);
  chunk_out<<<BBATCH * HH * CCHUNK, 256, 0, stream>>>(qb, kb, vb, Sbuf, zbuf, cAbuf,
                                                      GBeg, zGAgg, dpbuf);

  // Wo: r9-verified 8-wave gemm_db (f32 out)
  gemm_db<4><<<(MM / 256) * 4, 512, 0, stream>>>(qb, WoT, (float*)d_out);
}

// Round 18
// 243.576 us; speedup vs baseline: 1.1916x; 1.1916x over previous
//
#include <hip/hip_runtime.h>
#include <stdint.h>

#define HH 16
#define DH 64
#define DD 1024
#define PP 1024
#define NNLEN 8192
#define BBATCH 2
#define MM (BBATCH*NNLEN)   // 16384 rows
#define CCHUNK 128          // chunks per (b,h)
#define LCH 64              // chunk length
#define NGRP 16             // scan groups per (b,h)
#define GCH 8               // chunks per group
#define EPSV 1e-6f

typedef unsigned short u16;
typedef __attribute__((ext_vector_type(4))) unsigned short u16x4;
typedef __attribute__((ext_vector_type(8))) unsigned short u16x8;
typedef __attribute__((ext_vector_type(8))) __bf16 bf16x8;
typedef __attribute__((ext_vector_type(4))) float f32x4;

__device__ __forceinline__ u16 f2bf(float f) {
  unsigned x = __float_as_uint(f);
  return (u16)((x + 0x7fffu + ((x >> 16) & 1u)) >> 16);
}
__device__ __forceinline__ float bf2f(u16 u) {
  return __uint_as_float(((unsigned)u) << 16);
}

// async global->LDS, 16B per lane. LDS dest must be wave-uniform base.
__device__ __forceinline__ void gl2lds16(const void* g, void* l) {
  __builtin_amdgcn_global_load_lds(
      reinterpret_cast<__attribute__((address_space(1))) void*>(
          reinterpret_cast<uintptr_t>(g)),
      reinterpret_cast<__attribute__((address_space(3))) void*>(
          reinterpret_cast<uintptr_t>(l)),
      16, 0, 0);
}

// swizzled LDS read of a bf16x8 fragment from a [*][64] u16 tile.
__device__ __forceinline__ bf16x8 ldsw(const u16* base, int row, int col) {
  union { u16x8 u; bf16x8 b; } cv;
  cv.u = *(const u16x8*)&base[row * 64 + (col ^ ((row & 7) << 3))];
  return cv.b;
}

// ---------------------------------------------------------------------------
// prep_all (single launch): x convert + 4 weight transposes + Wa transpose
// ---------------------------------------------------------------------------
__global__ __launch_bounds__(256)
void prep_all(const float* __restrict__ x, u16* __restrict__ xb,
              const float* __restrict__ Wq, u16* __restrict__ WqT,
              const float* __restrict__ Wk, u16* __restrict__ WkT,
              const float* __restrict__ Wv, u16* __restrict__ WvT,
              const float* __restrict__ Wo, u16* __restrict__ WoT,
              const float* __restrict__ Wa, u16* __restrict__ WaT) {
  __shared__ float tile[32][33];
  const int bid = blockIdx.x;
  const int tid = threadIdx.x;
  if (bid < 8192) {
    size_t i = ((size_t)bid * 256 + tid) * 8;
    f32x4 a = *(const f32x4*)(x + i);
    f32x4 b = *(const f32x4*)(x + i + 4);
    u16x8 o;
    o[0] = f2bf(a[0]); o[1] = f2bf(a[1]); o[2] = f2bf(a[2]); o[3] = f2bf(a[3]);
    o[4] = f2bf(b[0]); o[5] = f2bf(b[1]); o[6] = f2bf(b[2]); o[7] = f2bf(b[3]);
    *(u16x8*)(xb + i) = o;
    return;
  }
  if (bid < 12288) {
    const int t = (bid - 8192) >> 10;
    const int sub = (bid - 8192) & 1023;
    const float* in = (t == 0) ? Wq : (t == 1) ? Wk : (t == 2) ? Wv : Wo;
    u16* out = (t == 0) ? WqT : (t == 1) ? WkT : (t == 2) ? WvT : WoT;
    const int bx = (sub & 31) * 32, by = (sub >> 5) * 32;
    const int tx = tid & 31, ty = tid >> 5;
    for (int i2 = ty; i2 < 32; i2 += 8)
      tile[i2][tx] = in[(size_t)(by + i2) * 1024 + bx + tx];
    __syncthreads();
    for (int i2 = ty; i2 < 32; i2 += 8)
      out[(size_t)(bx + i2) * 1024 + by + tx] = f2bf(tile[tx][i2]);
    return;
  }
  {
    int idx = (bid - 12288) * 256 + tid;
    WaT[idx] = f2bf(Wa[(idx & 1023) * 16 + (idx >> 10)]);
  }
}

// ---------------------------------------------------------------------------
// a_proj v2 (wide + double-buffered): abuf = sigmoid(xb @ Wa + ba + 2).
// grid = MM/64 = 256 blocks (all CUs), BM=64, BK=32, 4 waves (1 MFMA each),
// stage-first dbuf with ONE vmcnt(0)+barrier per K-step.
// ---------------------------------------------------------------------------
__global__ __launch_bounds__(256)
void a_proj(const u16* __restrict__ xb, const u16* __restrict__ WaT,
            const float* __restrict__ ba, float* __restrict__ abuf) {
  __shared__ __align__(16) u16 As[2][64 * 32];
  __shared__ __align__(16) u16 Bs[2][16 * 32];
  const int tid = threadIdx.x;
  const int brow = blockIdx.x * 64;
  const int l = tid & 63, wid = tid >> 6;
  const int la = l & 15, kb8 = (l >> 4) * 8;
  const int sr = tid >> 2, se = (tid & 3) * 8;

  f32x4 acc = (f32x4){0.f, 0.f, 0.f, 0.f};

  gl2lds16(xb + (size_t)(brow + sr) * DD + se, &As[0][wid * 512]);
  if (wid == 0)
    gl2lds16(WaT + (size_t)(l >> 2) * DD + (l & 3) * 8, &Bs[0][0]);
  asm volatile("s_waitcnt vmcnt(0)" ::: "memory");
  __builtin_amdgcn_s_barrier();

  for (int kt = 0; kt < 32; ++kt) {
    const bool more = (kt + 1 < 32);
    if (more) {
      const int kn = (kt + 1) * 32;
      gl2lds16(xb + (size_t)(brow + sr) * DD + kn + se,
               &As[(kt + 1) & 1][wid * 512]);
      if (wid == 0)
        gl2lds16(WaT + (size_t)(l >> 2) * DD + kn + (l & 3) * 8,
                 &Bs[(kt + 1) & 1][0]);
    }
    union { u16x8 u; bf16x8 b; } cva, cvb;
    cvb.u = *(const u16x8*)&Bs[kt & 1][la * 32 + kb8];
    cva.u = *(const u16x8*)&As[kt & 1][(wid * 16 + la) * 32 + kb8];
    acc = __builtin_amdgcn_mfma_f32_16x16x32_bf16(cva.b, cvb.b, acc, 0, 0, 0);
    if (more) {
      asm volatile("s_waitcnt vmcnt(0)" ::: "memory");
      __builtin_amdgcn_s_barrier();
    }
  }
  const float bav = ba[la];
#pragma unroll
  for (int rr = 0; rr < 4; ++rr) {
    int row = brow + wid * 16 + ((l >> 4) << 2) + rr;
    float t = acc[rr] + bav + 2.0f;
    abuf[(size_t)row * HH + la] = 1.f / (1.f + __expf(-t));
  }
}

// ---------------------------------------------------------------------------
// bf16 MFMA GEMM, 16-wave / 4-waves-per-SIMD (r14-verified: 1035 TF):
// 256x256 tile, BK=64, minimal-barrier stage-first, ONE vmcnt(0)+barrier
// per K-tile. Fused QKV (N=3072) routed bf16 epilogue w/ elu+1 on q/k.
// ---------------------------------------------------------------------------
template<int NCT>
__global__ __launch_bounds__(1024, 4)
void gemm16(const u16* __restrict__ A, const u16* __restrict__ Bt,
            void* __restrict__ Cout) {
  __shared__ __align__(16) u16 As[2][256 * 64];
  __shared__ __align__(16) u16 Bs[2][256 * 64];
  const int tid = threadIdx.x;
  const int nwg = gridDim.x;
  const int f = blockIdx.x;
  const int swz = (f & 7) * (nwg >> 3) + (f >> 3);
  const int brow = (swz / NCT) * 256;
  const int bcol = (swz % NCT) * 256;
  const int l = tid & 63;
  const int wid = tid >> 6;       // 0..15
  const int wr = wid >> 2;        // 0..3  (M quarter)
  const int wc = wid & 3;         // 0..3  (N quarter)
  const int la = l & 15, kb8 = (l >> 4) * 8;
  const int K = 1024;
  const int srow = l >> 3;
  const int scol = ((l & 7) * 8) ^ (srow << 3);
  const int ldso = (wid * 2) * 512;

  f32x4 acc[4][4];
#pragma unroll
  for (int i = 0; i < 4; ++i)
#pragma unroll
    for (int j = 0; j < 4; ++j) acc[i][j] = (f32x4){0.f, 0.f, 0.f, 0.f};

#pragma unroll
  for (int j = 0; j < 2; ++j) {
    const int r0 = (wid * 2 + j) * 8 + srow;
    gl2lds16(A  + (size_t)(brow + r0) * K + scol, &As[0][ldso + j * 512]);
    gl2lds16(Bt + (size_t)(bcol + r0) * K + scol, &Bs[0][ldso + j * 512]);
  }
  asm volatile("s_waitcnt vmcnt(0)" ::: "memory");
  __builtin_amdgcn_s_barrier();

  const int NKT = K / 64;
  for (int kt = 0; kt < NKT; ++kt) {
    const u16* lA = As[kt & 1];
    const u16* lB = Bs[kt & 1];
    u16* nA = As[(kt + 1) & 1];
    u16* nB = Bs[(kt + 1) & 1];
    const int knext = (kt + 1) * 64;
    const bool more = (kt + 1 < NKT);

    if (more) {
#pragma unroll
      for (int j = 0; j < 2; ++j) {
        const int r0 = (wid * 2 + j) * 8 + srow;
        gl2lds16(A  + (size_t)(brow + r0) * K + knext + scol,
                 nA + ldso + j * 512);
        gl2lds16(Bt + (size_t)(bcol + r0) * K + knext + scol,
                 nB + ldso + j * 512);
      }
    }

    bf16x8 bfr[4][2];
#pragma unroll
    for (int n2 = 0; n2 < 4; ++n2)
#pragma unroll
      for (int kk = 0; kk < 2; ++kk)
        bfr[n2][kk] = ldsw(lB, wc * 64 + n2 * 16 + la, kk * 32 + kb8);

#pragma unroll
    for (int m2 = 0; m2 < 4; ++m2) {
      bf16x8 af0 = ldsw(lA, wr * 64 + m2 * 16 + la, kb8);
      bf16x8 af1 = ldsw(lA, wr * 64 + m2 * 16 + la, 32 + kb8);
      __builtin_amdgcn_s_setprio(1);
#pragma unroll
      for (int n2 = 0; n2 < 4; ++n2) {
        acc[m2][n2] = __builtin_amdgcn_mfma_f32_16x16x32_bf16(
            af0, bfr[n2][0], acc[m2][n2], 0, 0, 0);
        acc[m2][n2] = __builtin_amdgcn_mfma_f32_16x16x32_bf16(
            af1, bfr[n2][1], acc[m2][n2], 0, 0, 0);
      }
      __builtin_amdgcn_s_setprio(0);
    }

    if (more) {
      asm volatile("s_waitcnt vmcnt(0)" ::: "memory");
      __builtin_amdgcn_s_barrier();
    }
  }

  const int wrow = wr * 64, wcol = wc * 64;
  u16* base = (u16*)Cout + (size_t)(bcol >> 10) * ((size_t)MM * 1024);
  const bool act = (bcol < 2048);
#pragma unroll
  for (int mi = 0; mi < 4; ++mi)
#pragma unroll
    for (int ni = 0; ni < 4; ++ni)
#pragma unroll
      for (int rr = 0; rr < 4; ++rr) {
        int row = brow + wrow + mi * 16 + ((l >> 4) << 2) + rr;
        int c2 = (bcol & 1023) + wcol + ni * 16 + la;
        float v = acc[mi][ni][rr];
        if (act) v = v > 0.f ? v + 1.f : __expf(v);
        base[(size_t)row * 1024 + c2] = f2bf(v);
      }
}

// ---------------------------------------------------------------------------
// bf16 MFMA GEMM, 8-wave / 512-thread (r9-verified for Wo, f32 out).
// ---------------------------------------------------------------------------
template<int NCT>
__global__ __launch_bounds__(512)
void gemm_db(const u16* __restrict__ A, const u16* __restrict__ Bt,
             float* __restrict__ Cout) {
  __shared__ __align__(16) u16 As[2][256 * 64];
  __shared__ __align__(16) u16 Bs[2][256 * 64];
  const int tid = threadIdx.x;
  const int nwg = gridDim.x;
  const int f = blockIdx.x;
  const int swz = (f & 7) * (nwg >> 3) + (f >> 3);
  const int brow = (swz / NCT) * 256;
  const int bcol = (swz % NCT) * 256;
  const int l = tid & 63;
  const int wid = tid >> 6;
  const int wr = wid >> 2;
  const int wc = wid & 3;
  const int la = l & 15, kb8 = (l >> 4) * 8;
  const int K = 1024;
  const int srow = l >> 3;
  const int scol = ((l & 7) * 8) ^ (srow << 3);
  const int ldso = (wid * 2) * 512;

  f32x4 acc[8][4];
#pragma unroll
  for (int i = 0; i < 8; ++i)
#pragma unroll
    for (int j = 0; j < 4; ++j) acc[i][j] = (f32x4){0.f, 0.f, 0.f, 0.f};

#pragma unroll
  for (int h = 0; h < 2; ++h)
#pragma unroll
    for (int j = 0; j < 2; ++j) {
      const int r0 = h * 128 + (wid * 2 + j) * 8 + srow;
      gl2lds16(A  + (size_t)(brow + r0) * K + scol, &As[0][h * 8192 + ldso + j * 512]);
      gl2lds16(Bt + (size_t)(bcol + r0) * K + scol, &Bs[0][h * 8192 + ldso + j * 512]);
    }
  asm volatile("s_waitcnt vmcnt(0)" ::: "memory");
  __builtin_amdgcn_s_barrier();

  const int NKT = K / 64;
  for (int kt = 0; kt < NKT; ++kt) {
    const u16* lA = As[kt & 1];
    const u16* lB = Bs[kt & 1];
    u16* nA = As[(kt + 1) & 1];
    u16* nB = Bs[(kt + 1) & 1];
    const int knext = (kt + 1) * 64;
    const bool more = (kt + 1 < NKT);

    if (more) {
#pragma unroll
      for (int h = 0; h < 2; ++h)
#pragma unroll
        for (int j = 0; j < 2; ++j) {
          const int r0 = h * 128 + (wid * 2 + j) * 8 + srow;
          gl2lds16(A  + (size_t)(brow + r0) * K + knext + scol,
                   nA + h * 8192 + ldso + j * 512);
          gl2lds16(Bt + (size_t)(bcol + r0) * K + knext + scol,
                   nB + h * 8192 + ldso + j * 512);
        }
    }

    bf16x8 af[4][2], bfr[4][2];
#pragma unroll
    for (int m2 = 0; m2 < 4; ++m2)
#pragma unroll
      for (int kk = 0; kk < 2; ++kk)
        af[m2][kk] = ldsw(lA, wr * 128 + m2 * 16 + la, kk * 32 + kb8);
#pragma unroll
    for (int n2 = 0; n2 < 4; ++n2)
#pragma unroll
      for (int kk = 0; kk < 2; ++kk)
        bfr[n2][kk] = ldsw(lB, wc * 64 + n2 * 16 + la, kk * 32 + kb8);

    __builtin_amdgcn_s_setprio(1);
#pragma unroll
    for (int m2 = 0; m2 < 4; ++m2)
#pragma unroll
      for (int n2 = 0; n2 < 4; ++n2)
#pragma unroll
        for (int kk = 0; kk < 2; ++kk)
          acc[m2][n2] = __builtin_amdgcn_mfma_f32_16x16x32_bf16(
              af[m2][kk], bfr[n2][kk], acc[m2][n2], 0, 0, 0);
    __builtin_amdgcn_s_setprio(0);

#pragma unroll
    for (int m2 = 0; m2 < 4; ++m2)
#pragma unroll
      for (int kk = 0; kk < 2; ++kk)
        af[m2][kk] = ldsw(lA, wr * 128 + 64 + m2 * 16 + la, kk * 32 + kb8);

    __builtin_amdgcn_s_setprio(1);
#pragma unroll
    for (int m2 = 0; m2 < 4; ++m2)
#pragma unroll
      for (int n2 = 0; n2 < 4; ++n2)
#pragma unroll
        for (int kk = 0; kk < 2; ++kk)
          acc[4 + m2][n2] = __builtin_amdgcn_mfma_f32_16x16x32_bf16(
              af[m2][kk], bfr[n2][kk], acc[4 + m2][n2], 0, 0, 0);
    __builtin_amdgcn_s_setprio(0);

    if (more) {
      asm volatile("s_waitcnt vmcnt(0)" ::: "memory");
      __builtin_amdgcn_s_barrier();
    }
  }

  const int wrow = wr * 128, wcol = wc * 64;
#pragma unroll
  for (int mi = 0; mi < 8; ++mi)
#pragma unroll
    for (int ni = 0; ni < 4; ++ni)
#pragma unroll
      for (int rr = 0; rr < 4; ++rr) {
        int row = brow + wrow + mi * 16 + ((l >> 4) << 2) + rr;
        int col = bcol + wcol + ni * 16 + la;
        Cout[(size_t)row * 1024 + col] = acc[mi][ni][rr];
      }
}

// ---------------------------------------------------------------------------
// FUSED Kernel A + scan level 1, cA-hoisted + k/v software pipeline.
// ---------------------------------------------------------------------------
__global__ __launch_bounds__(256)
void chunk_local_scan(const u16* __restrict__ kb, const u16* __restrict__ vb,
                      const float* __restrict__ abuf,
                      u16* __restrict__ Sbuf, float* __restrict__ zbuf,
                      float* __restrict__ cAbuf,
                      float* __restrict__ GAgg, float* __restrict__ zGAgg,
                      float* __restrict__ dpbuf) {
  const int g = blockIdx.x & (NGRP - 1);
  const int bh = blockIdx.x >> 4;
  const int h = bh & (HH - 1);
  const int b = bh >> 4;
  __shared__ __align__(16) u16 KT[64 * 64];
  __shared__ __align__(16) u16 VTl[64 * 64];
  __shared__ float wshA[GCH][64];
  __shared__ float dchA[GCH];
  const int tid = threadIdx.x;
  const int r = tid >> 2, e = (tid & 3) * 16;
  const int l = tid & 63, w = tid >> 6;
  const int kb8 = (l >> 4) << 3, la = l & 15;
  const int dw = 16 * w + ((l >> 4) << 2);
  const int dkz = tid >> 2, tqz = (tid & 3) * 16, swkz = (dkz & 7) << 3;
  const int c0 = g * GCH;
  const int rowbase0 = b * NNLEN + c0 * LCH;

#pragma unroll
  for (int ii = 0; ii < 2; ++ii) {
    const int i = w * 2 + ii;
    const int blkc = bh * CCHUNK + c0 + i;
    float v = __logf(abuf[(size_t)(rowbase0 + i * LCH + l) * HH + h]);
#pragma unroll
    for (int d = 1; d < 64; d <<= 1) {
      float u = __shfl_up(v, d);
      if (l >= d) v += u;
    }
    cAbuf[(size_t)blkc * 64 + l] = v;
    float tot = __shfl(v, 63);
    wshA[i][l] = __expf(tot - v);
    if (l == 0) dchA[i] = __expf(tot);
  }
  __syncthreads();
  if (tid == 0) {
    float rp = 1.f;
#pragma unroll
    for (int i = 0; i < GCH; ++i) {
      dpbuf[bh * CCHUNK + c0 + i] = rp;
      rp *= dchA[i];
    }
  }

  f32x4 run[4];
#pragma unroll
  for (int ni = 0; ni < 4; ++ni) run[ni] = (f32x4){0.f, 0.f, 0.f, 0.f};
  float zrun = 0.f;

  const u16* kp = kb + (size_t)(rowbase0 + r) * PP + h * DH + e;
  const u16* vp = vb + (size_t)(rowbase0 + r) * PP + h * DH + e;
  u16x8 k0 = *(const u16x8*)kp, k1 = *(const u16x8*)(kp + 8);
  u16x8 v0 = *(const u16x8*)vp, v1 = *(const u16x8*)(vp + 8);

  for (int i = 0; i < GCH; ++i) {
    const int blkc = bh * CCHUNK + c0 + i;
    if (i) __syncthreads();

    {
      const float wt = wshA[i][r];
#pragma unroll
      for (int j = 0; j < 8; ++j) {
        int d0 = e + j, d1 = e + 8 + j;
        KT[d0 * 64 + (r ^ ((d0 & 7) << 3))] = f2bf(bf2f(k0[j]) * wt);
        KT[d1 * 64 + (r ^ ((d1 & 7) << 3))] = f2bf(bf2f(k1[j]) * wt);
        VTl[d0 * 64 + (r ^ ((d0 & 7) << 3))] = v0[j];
        VTl[d1 * 64 + (r ^ ((d1 & 7) << 3))] = v1[j];
      }
    }
    __syncthreads();

    if (i + 1 < GCH) {
      const int rb = rowbase0 + (i + 1) * LCH;
      kp = kb + (size_t)(rb + r) * PP + h * DH + e;
      vp = vb + (size_t)(rb + r) * PP + h * DH + e;
      k0 = *(const u16x8*)kp; k1 = *(const u16x8*)(kp + 8);
      v0 = *(const u16x8*)vp; v1 = *(const u16x8*)(vp + 8);
    }

    const float dch = dchA[i];
    f32x4 s[4];
#pragma unroll
    for (int ni = 0; ni < 4; ++ni) s[ni] = (f32x4){0.f, 0.f, 0.f, 0.f};
#pragma unroll
    for (int kk = 0; kk < 2; ++kk) {
      bf16x8 av = ldsw(VTl, 16 * w + la, kk * 32 + kb8);
#pragma unroll
      for (int ni = 0; ni < 4; ++ni)
        s[ni] = __builtin_amdgcn_mfma_f32_16x16x32_bf16(
            av, ldsw(KT, 16 * ni + la, kk * 32 + kb8), s[ni], 0, 0, 0);
    }

    u16* Sc = Sbuf + (size_t)blkc * 4096;
#pragma unroll
    for (int ni = 0; ni < 4; ++ni)
#pragma unroll
      for (int rr = 0; rr < 4; ++rr)
        Sc[(dw + rr) * 64 + 16 * ni + la] = f2bf(run[ni][rr]);
#pragma unroll
    for (int ni = 0; ni < 4; ++ni)
#pragma unroll
      for (int rr = 0; rr < 4; ++rr)
        run[ni][rr] = dch * run[ni][rr] + s[ni][rr];

    {
      float zp = 0.f;
#pragma unroll
      for (int i2 = 0; i2 < 16; ++i2)
        zp += bf2f(KT[dkz * 64 + ((tqz + i2) ^ swkz)]);
      zp += __shfl_xor(zp, 1);
      zp += __shfl_xor(zp, 2);
      if ((tid & 3) == 0) zbuf[(size_t)blkc * 64 + dkz] = zrun;
      zrun = dch * zrun + zp;
    }
  }

  float* Ga = GAgg + ((size_t)bh * NGRP + g) * 4096;
#pragma unroll
  for (int ni = 0; ni < 4; ++ni)
#pragma unroll
    for (int rr = 0; rr < 4; ++rr)
      Ga[(dw + rr) * 64 + 16 * ni + la] = run[ni][rr];
  if ((tid & 3) == 0)
    zGAgg[((size_t)bh * NGRP + g) * 64 + dkz] = zrun;
}

// ---------------------------------------------------------------------------
// Scan level 2: across the 16 group aggregates. GAgg(f32) -> GBeg (bf16).
// ---------------------------------------------------------------------------
__global__ __launch_bounds__(1024)
void scan_top(const float* __restrict__ GAgg, u16* __restrict__ GBeg,
              float* __restrict__ zGAgg, const float* __restrict__ cAbuf) {
  const int bh = blockIdx.x;
  const size_t cb = (size_t)bh * CCHUNK;
  __shared__ float Dsh[NGRP];
  if (threadIdx.x < NGRP) {
    float s = 0.f;
#pragma unroll
    for (int i = 0; i < GCH; ++i)
      s += cAbuf[(cb + threadIdx.x * GCH + i) * 64 + 63];
    Dsh[threadIdx.x] = __expf(s);
  }
  __syncthreads();
  const int elem = threadIdx.x * 4;
  const float* base = GAgg + (size_t)bh * NGRP * 4096;
  u16* gb = GBeg + (size_t)bh * NGRP * 4096;
  f32x4 run = (f32x4){0.f, 0.f, 0.f, 0.f};
  f32x4 cur = *(const f32x4*)&base[elem];
#pragma unroll
  for (int gg = 0; gg < NGRP; ++gg) {
    f32x4 nxt;
    if (gg + 1 < NGRP) nxt = *(const f32x4*)&base[(gg + 1) * 4096 + elem];
    u16x4 o;
#pragma unroll
    for (int jj = 0; jj < 4; ++jj) o[jj] = f2bf(run[jj]);
    *(u16x4*)&gb[gg * 4096 + elem] = o;
    const float D = Dsh[gg];
#pragma unroll
    for (int jj = 0; jj < 4; ++jj) run[jj] = D * run[jj] + cur[jj];
    cur = nxt;
  }
  if (threadIdx.x < 64) {
    float* zb = zGAgg + (size_t)bh * NGRP * 64;
    float zr = 0.f;
#pragma unroll
    for (int gg = 0; gg < NGRP; ++gg) {
      float a = zb[gg * 64 + threadIdx.x];
      zb[gg * 64 + threadIdx.x] = zr;
      zr = Dsh[gg] * zr + a;
    }
  }
}

// ---------------------------------------------------------------------------
// Kernel C (MFMA): per-chunk output (r16-verified).
// ---------------------------------------------------------------------------
__global__ __launch_bounds__(256)
void chunk_out(u16* __restrict__ qb, const u16* __restrict__ kb,
               const u16* __restrict__ vb, const u16* __restrict__ Sbuf,
               const float* __restrict__ zbuf, const float* __restrict__ cAbuf,
               const u16* __restrict__ GBeg, const float* __restrict__ zGAgg,
               const float* __restrict__ dpbuf) {
  const int blk = blockIdx.x;
  const int c = blk & (CCHUNK - 1);
  const int h = (blk >> 7) & (HH - 1);
  const int b = blk >> 11;
  const int bh = blk >> 7;
  const int g = c >> 3;
  const int rowbase = b * NNLEN + c * LCH;

  __shared__ __align__(16) u16 Qs[64 * 64];
  __shared__ __align__(16) u16 Ke[64 * 64];   // Ke, later reused as P tile
  __shared__ __align__(16) u16 VT[64 * 64];
  __shared__ __align__(16) u16 STs[64 * 64];
  __shared__ float cAsh[64], zsh[64], denP[64], qzs[64];

  const int tid = threadIdx.x;
  const int r = tid >> 2, e = (tid & 3) * 16;
  const float dp = dpbuf[blk];

  const u16* qp = qb + (size_t)(rowbase + r) * PP + h * DH + e;
  const u16* kp = kb + (size_t)(rowbase + r) * PP + h * DH + e;
  const u16* vp = vb + (size_t)(rowbase + r) * PP + h * DH + e;
  u16x8 q0 = *(const u16x8*)qp, q1 = *(const u16x8*)(qp + 8);
  u16x8 k0 = *(const u16x8*)kp, k1 = *(const u16x8*)(kp + 8);
  u16x8 v0 = *(const u16x8*)vp, v1 = *(const u16x8*)(vp + 8);
  const u16* sp = Sbuf + (size_t)blk * 4096 + r * 64 + e;
  u16x8 p0 = *(const u16x8*)sp, p1 = *(const u16x8*)(sp + 8);
  const u16* gp = GBeg + ((size_t)bh * NGRP + g) * 4096 + r * 64 + e;
  u16x8 gb0 = *(const u16x8*)gp, gb1 = *(const u16x8*)(gp + 8);
  if (tid < 64) {
    cAsh[tid] = cAbuf[(size_t)blk * 64 + tid];
    zsh[tid] = zbuf[(size_t)blk * 64 + tid]
             + dp * zGAgg[((size_t)bh * NGRP + g) * 64 + tid];
  }
  __syncthreads();

  {
    const float c0c = cAsh[31];
    const int sw = (r & 7) << 3;
    const float qsc = __expf(cAsh[r] - c0c);
    const float ksc = __expf(c0c - cAsh[r]);
    const float ssc = __expf(c0c);
    u16x8 t0, t1, u0, u1, w0, w1;
#pragma unroll
    for (int j = 0; j < 8; ++j) {
      t0[j] = f2bf(bf2f(q0[j]) * qsc);
      t1[j] = f2bf(bf2f(q1[j]) * qsc);
      u0[j] = f2bf(bf2f(k0[j]) * ksc);
      u1[j] = f2bf(bf2f(k1[j]) * ksc);
    }
#pragma unroll
    for (int j = 0; j < 8; ++j) {
      w0[j] = f2bf((bf2f(p0[j]) + dp * bf2f(gb0[j])) * ssc);
      w1[j] = f2bf((bf2f(p1[j]) + dp * bf2f(gb1[j])) * ssc);
    }
    *(u16x8*)&Qs[r * 64 + (e ^ sw)] = t0;
    *(u16x8*)&Qs[r * 64 + ((e + 8) ^ sw)] = t1;
    *(u16x8*)&Ke[r * 64 + (e ^ sw)] = u0;
    *(u16x8*)&Ke[r * 64 + ((e + 8) ^ sw)] = u1;
    *(u16x8*)&STs[r * 64 + (e ^ sw)] = w0;
    *(u16x8*)&STs[r * 64 + ((e + 8) ^ sw)] = w1;
#pragma unroll
    for (int j = 0; j < 8; ++j) {
      int d0 = e + j, d1 = e + 8 + j;
      VT[d0 * 64 + (r ^ ((d0 & 7) << 3))] = v0[j];
      VT[d1 * 64 + (r ^ ((d1 & 7) << 3))] = v1[j];
    }
    if (tid < 64) zsh[tid] *= ssc;
  }
  __syncthreads();

  const int l = tid & 63, w = tid >> 6;
  const int kb8 = (l >> 4) << 3, la = l & 15;

  // --- MFMA1: P = Qe @ Ke^T ---
  bf16x8 aq[2];
  f32x4 p[4];
#pragma unroll
  for (int ni = 0; ni < 4; ++ni) p[ni] = (f32x4){0.f, 0.f, 0.f, 0.f};
#pragma unroll
  for (int kk = 0; kk < 2; ++kk) {
    aq[kk] = ldsw(Qs, 16 * w + la, kk * 32 + kb8);
#pragma unroll
    for (int ni = 0; ni < 4; ++ni)
      p[ni] = __builtin_amdgcn_mfma_f32_16x16x32_bf16(
          aq[kk], ldsw(Ke, 16 * ni + la, kk * 32 + kb8), p[ni], 0, 0, 0);
  }

  const int tw = 16 * w + ((l >> 4) << 2);
  float rsum[4] = {0.f, 0.f, 0.f, 0.f};
#pragma unroll
  for (int ni = 0; ni < 4; ++ni)
#pragma unroll
    for (int rr = 0; rr < 4; ++rr) {
      int s = 16 * ni + la, t = tw + rr;
      float v = (s <= t) ? p[ni][rr] : 0.f;
      p[ni][rr] = v;
      rsum[rr] += v;
    }
#pragma unroll
  for (int d = 1; d < 16; d <<= 1)
#pragma unroll
    for (int rr = 0; rr < 4; ++rr) rsum[rr] += __shfl_xor(rsum[rr], d);
  if (la == 0)
#pragma unroll
    for (int rr = 0; rr < 4; ++rr) denP[tw + rr] = rsum[rr];

  // qz[row] = Qe[row] . z0e from register fragments
  {
    float qzp = 0.f;
#pragma unroll
    for (int kk = 0; kk < 2; ++kk)
#pragma unroll
      for (int j = 0; j < 8; ++j) {
        union { bf16x8 b; u16x8 u; } cv; cv.b = aq[kk];
        qzp += bf2f(cv.u[j]) * zsh[kk * 32 + kb8 + j];
      }
    qzp += __shfl_xor(qzp, 16);
    qzp += __shfl_xor(qzp, 32);
    if (l < 16) qzs[16 * w + la] = qzp;
  }
  __syncthreads();   // all waves done reading Qs/Ke -> Ke reusable as P

  // write P into (dead) Ke tile, swizzled
#pragma unroll
  for (int ni = 0; ni < 4; ++ni)
#pragma unroll
    for (int rr = 0; rr < 4; ++rr) {
      int t = tw + rr, s = 16 * ni + la;
      Ke[t * 64 + (s ^ ((t & 7) << 3))] = f2bf(p[ni][rr]);
    }
  __syncthreads();

  // --- MFMA2: O = P@V + Qe@S0e^T ---
  f32x4 o[4];
#pragma unroll
  for (int ni = 0; ni < 4; ++ni) o[ni] = (f32x4){0.f, 0.f, 0.f, 0.f};
#pragma unroll
  for (int kk = 0; kk < 2; ++kk) {
    bf16x8 ap = ldsw(Ke, 16 * w + la, kk * 32 + kb8);
#pragma unroll
    for (int ni = 0; ni < 4; ++ni)
      o[ni] = __builtin_amdgcn_mfma_f32_16x16x32_bf16(
          ap, ldsw(VT, 16 * ni + la, kk * 32 + kb8), o[ni], 0, 0, 0);
  }
#pragma unroll
  for (int kk = 0; kk < 2; ++kk)
#pragma unroll
    for (int ni = 0; ni < 4; ++ni)
      o[ni] = __builtin_amdgcn_mfma_f32_16x16x32_bf16(
          aq[kk], ldsw(STs, 16 * ni + la, kk * 32 + kb8), o[ni], 0, 0, 0);

  float dn[4];
#pragma unroll
  for (int rr = 0; rr < 4; ++rr) dn[rr] = qzs[tw + rr] + denP[tw + rr] + EPSV;
#pragma unroll
  for (int ni = 0; ni < 4; ++ni)
#pragma unroll
    for (int rr = 0; rr < 4; ++rr) {
      int t = tw + rr, dv = 16 * ni + la;
      qb[(size_t)(rowbase + t) * PP + h * DH + dv] = f2bf(o[ni][rr] / dn[rr]);
    }
}

// ---------------------------------------------------------------------------
extern "C" void kernel_launch(void* const* d_in, const int* in_sizes, int n_in,
                              void* d_out, int out_size, void* d_ws, size_t ws_size,
                              hipStream_t stream) {
  const float* x  = (const float*)d_in[0];
  const float* Wq = (const float*)d_in[1];
  const float* Wk = (const float*)d_in[2];
  const float* Wv = (const float*)d_in[3];
  const float* Wo = (const float*)d_in[4];
  const float* Wa = (const float*)d_in[5];
  const float* ba = (const float*)d_in[6];

  char* ws = (char*)d_ws;
  size_t off = 0;
  auto carve = [&](size_t bytes) {
    void* p = ws + off;
    off += (bytes + 255) & ~(size_t)255;
    return p;
  };
  u16* xb   = (u16*)carve((size_t)MM * DD * 2);
  u16* WqT  = (u16*)carve((size_t)PP * DD * 2);  // WqT/WkT/WvT contiguous
  u16* WkT  = (u16*)carve((size_t)PP * DD * 2);
  u16* WvT  = (u16*)carve((size_t)PP * DD * 2);
  u16* WoT  = (u16*)carve((size_t)DD * PP * 2);
  u16* WaT  = (u16*)carve((size_t)HH * DD * 2);
  u16* qb   = (u16*)carve((size_t)MM * PP * 2);  // qb/kb/vb contiguous
  u16* kb   = (u16*)carve((size_t)MM * PP * 2);
  u16* vb   = (u16*)carve((size_t)MM * PP * 2);
  float* abuf  = (float*)carve((size_t)MM * HH * 4);
  u16*  Sbuf   = (u16*)carve((size_t)BBATCH * HH * CCHUNK * 4096 * 2);
  float* zbuf  = (float*)carve((size_t)BBATCH * HH * CCHUNK * 64 * 4);
  float* cAbuf = (float*)carve((size_t)BBATCH * HH * CCHUNK * 64 * 4);
  float* GAgg  = (float*)carve((size_t)BBATCH * HH * NGRP * 4096 * 4);
  u16*  GBeg   = (u16*)carve((size_t)BBATCH * HH * NGRP * 4096 * 2);
  float* zGAgg = (float*)carve((size_t)BBATCH * HH * NGRP * 64 * 4);
  float* dpbuf = (float*)carve((size_t)BBATCH * HH * CCHUNK * 4);

  prep_all<<<12352, 256, 0, stream>>>(x, xb, Wq, WqT, Wk, WkT, Wv, WvT,
                                      Wo, WoT, Wa, WaT);
  // widened dbuf a_proj: 256 blocks (BM=64)
  a_proj<<<MM / 64, 256, 0, stream>>>(xb, WaT, ba, abuf);

  // fused QKV: M=16384, N=3072, 16-wave blocks (r14-verified 1035 TF)
  gemm16<12><<<(MM / 256) * 12, 1024, 0, stream>>>(xb, WqT, qb);

  chunk_local_scan<<<BBATCH * HH * NGRP, 256, 0, stream>>>(
      kb, vb, abuf, Sbuf, zbuf, cAbuf, GAgg, zGAgg, dpbuf);
  scan_top<<<BBATCH * HH, 1024, 0, stream>>>(GAgg, GBeg, zGAgg, cAbuf);
  chunk_out<<<BBATCH * HH * CCHUNK, 256, 0, stream>>>(qb, kb, vb, Sbuf, zbuf, cAbuf,
                                                      GBeg, zGAgg, dpbuf);

  // Wo: r9-verified 8-wave gemm_db (f32 out)
  gemm_db<4><<<(MM / 256) * 4, 512, 0, stream>>>(qb, WoT, (float*)d_out);
}